// Round 2
// baseline (3408.105 us; speedup 1.0000x reference)
//
#include <hip/hip_runtime.h>

// NodeGCN: GCNConv + 2x GINConv (edge-attr MLPs) + BN + concat + 2-layer head.
// Round 2: edge MLP -> bf16 MFMA (16x16x32), 34KB LDS (4 blocks/CU), no barriers
// in tile loop, swapped GEMM2 so each lane owns 4 consecutive feats of one edge.
// ws layout: [deg (256KB pad)][hbuf 19.2MB][tmp/agg 19.2MB][feats 57.6MB]

#define HH 96
#define EDGEF 16
#define CAT (3 * HH)

typedef __attribute__((ext_vector_type(8))) short bf16x8;
typedef __attribute__((ext_vector_type(4))) float f32x4;

__device__ __forceinline__ short f2bf(float f) {
    unsigned u = __float_as_uint(f);
    u += 0x7fffu + ((u >> 16) & 1u);      // round-to-nearest-even
    return (short)(u >> 16);
}

// ---------------- generic tiled GEMM: C[M,F] = act(A[M,K] @ W[K,F] + b) ----------
template <int F, bool RELU>
__global__ __launch_bounds__(256) void gemm_kernel(
    const float* __restrict__ A, int lda,
    const float* __restrict__ W,
    const float* __restrict__ bias,
    float* __restrict__ C, int ldc,
    int M, int K)
{
    constexpr int BM = 64, BK = 32;
    constexpr int FPT = F / 16;
    __shared__ float As[BM][BK + 1];
    __shared__ float Ws[BK][F];

    const int tid = threadIdx.x;
    const int ty = tid >> 4, tx = tid & 15;
    const int m0 = blockIdx.x * BM;

    float acc[4][FPT];
#pragma unroll
    for (int i = 0; i < 4; ++i)
#pragma unroll
        for (int j = 0; j < FPT; ++j) acc[i][j] = 0.f;

    for (int k0 = 0; k0 < K; k0 += BK) {
        __syncthreads();
#pragma unroll
        for (int i = 0; i < (BM * BK) / 256; ++i) {
            int idx = i * 256 + tid;
            int r = idx >> 5, c = idx & 31;
            int gr = m0 + r;
            As[r][c] = (gr < M) ? A[(long)gr * lda + k0 + c] : 0.f;
        }
#pragma unroll
        for (int i = 0; i < (BK * F) / 256; ++i) {
            int idx = i * 256 + tid;
            int k = idx / F, f = idx % F;
            Ws[k][f] = W[(long)(k0 + k) * F + f];
        }
        __syncthreads();
#pragma unroll
        for (int k = 0; k < BK; ++k) {
            float a[4], w[FPT];
#pragma unroll
            for (int i = 0; i < 4; ++i) a[i] = As[ty + i * 16][k];
#pragma unroll
            for (int j = 0; j < FPT; ++j) w[j] = Ws[k][tx + j * 16];
#pragma unroll
            for (int i = 0; i < 4; ++i)
#pragma unroll
                for (int j = 0; j < FPT; ++j)
                    acc[i][j] = fmaf(a[i], w[j], acc[i][j]);
        }
    }

#pragma unroll
    for (int i = 0; i < 4; ++i) {
        int r = m0 + ty + i * 16;
        if (r < M) {
#pragma unroll
            for (int j = 0; j < FPT; ++j) {
                int f = tx + j * 16;
                float v = acc[i][j] + bias[f];
                if (RELU) v = fmaxf(v, 0.f);
                C[(long)r * ldc + f] = v;
            }
        }
    }
}

// ---------------- fused MFMA edge kernel -----------------------------------------
// per edge: ee = relu(ea@bw1+bb1)@bw2+bb2 ; msg = [nrm*]relu(h[row]+ee) ;
// atomicAdd(agg[col], msg).
// 4 waves/block; wave w owns edges [e0+16w, e0+16w+16). s_t is wave-private,
// s_bw2T read-only after prologue -> NO barriers in the tile loop.
// GEMM1: t[e][f] = ea @ bw1         (D rows=edges, cols=feats)
// GEMM2 swapped: ee^T[f][e] = bw2^T @ t^T  -> lane owns edge (lane&15),
//   feats 16*ft + 4*(lane>>4) + {0..3}  => float4 gather + line-local atomics.
template <bool GCN>
__global__ __launch_bounds__(256, 4) void edge_kernel(
    const float* __restrict__ edge_attr,
    const int* __restrict__ row, const int* __restrict__ col,
    const float* __restrict__ bw1, const float* __restrict__ bb1,
    const float* __restrict__ bw2, const float* __restrict__ bb2,
    const float* __restrict__ h, int h_stride,
    const float* __restrict__ deg,
    float* __restrict__ agg,
    int E)
{
    __shared__ __align__(16) short s_bw2T[96][104];  // bw2^T, bf16: [f][k]  19968 B
    __shared__ __align__(16) short s_t[64][104];     // t, bf16: [edge][feat] 13312 B
    __shared__ float s_bias[192];                    // bb1 | bb2              768 B

    const int tid = threadIdx.x;
    const int lane = tid & 63;
    const int w = tid >> 6;          // wave 0..3
    const int lr = lane & 15;
    const int lg = lane >> 4;        // 0..3

    // ---- prologue: stage bw2^T (bf16) + biases ----
    for (int idx = tid; idx < HH * HH; idx += 256) {
        int k = idx / HH, f = idx - k * HH;
        s_bw2T[f][k] = f2bf(bw2[idx]);
    }
    if (tid < HH) { s_bias[tid] = bb1[tid]; s_bias[HH + tid] = bb2[tid]; }

    // ---- persistent bw1 B-frags in registers (lanes with k<16 only) ----
    bf16x8 bwf[6];
#pragma unroll
    for (int ft = 0; ft < 6; ++ft)
#pragma unroll
        for (int j = 0; j < 8; ++j) bwf[ft][j] = 0;
    if (lg < 2) {
#pragma unroll
        for (int ft = 0; ft < 6; ++ft)
#pragma unroll
            for (int j = 0; j < 8; ++j)
                bwf[ft][j] = f2bf(bw1[(8 * lg + j) * HH + lr + 16 * ft]);
    }
    __syncthreads();

    const f32x4 zf = {0.f, 0.f, 0.f, 0.f};
    const int ntiles = (E + 63) >> 6;

    for (int tile = blockIdx.x; tile < ntiles; tile += gridDim.x) {
        const int e0 = tile << 6;
        const int eg = e0 + 16 * w + lr;            // this lane's edge
        const int egc = (eg < E) ? eg : (E - 1);
        const bool valid = (eg < E);

        // ---- GEMM1 A-frag: ea[edge][k], k = 8*lg + j (zero for k>=16) ----
        bf16x8 ae;
#pragma unroll
        for (int j = 0; j < 8; ++j) ae[j] = 0;
        if (lg < 2) {
            const float* ep = edge_attr + (size_t)egc * EDGEF + 8 * lg;
            f32x4 a0 = *(const f32x4*)ep;
            f32x4 a1 = *(const f32x4*)(ep + 4);
#pragma unroll
            for (int j = 0; j < 4; ++j) { ae[j] = f2bf(a0[j]); ae[4 + j] = f2bf(a1[j]); }
        }

        // ---- GEMM1 + bias + relu -> s_t (wave-private rows) ----
#pragma unroll
        for (int ft = 0; ft < 6; ++ft) {
            f32x4 tacc = __builtin_amdgcn_mfma_f32_16x16x32_bf16(ae, bwf[ft], zf, 0, 0, 0);
            float b = s_bias[lr + 16 * ft];
#pragma unroll
            for (int reg = 0; reg < 4; ++reg) {
                float v = fmaxf(tacc[reg] + b, 0.f);
                s_t[16 * w + 4 * lg + reg][lr + 16 * ft] = f2bf(v);
            }
        }

        // ---- GEMM2 B-frags: t^T[k][edge] -> read own row of s_t ----
        bf16x8 bt[3];
#pragma unroll
        for (int kt = 0; kt < 3; ++kt)
            bt[kt] = *(const bf16x8*)&s_t[16 * w + lr][8 * lg + 32 * kt];

        // ---- per-edge metadata (4 lanes share an edge; redundant, cached) ----
        const int r = row[egc];
        const int c = col[egc];
        float nrm = 1.f;
        if (GCN) nrm = rsqrtf(deg[r]) * rsqrtf(deg[c]);
        const float* hrow = h + (size_t)r * h_stride;

        // ---- GEMM2 (swapped) + epilogue ----
#pragma unroll
        for (int ft = 0; ft < 6; ++ft) {
            f32x4 ee = zf;
#pragma unroll
            for (int kt = 0; kt < 3; ++kt) {
                bf16x8 aw = *(const bf16x8*)&s_bw2T[lr + 16 * ft][8 * lg + 32 * kt];
                ee = __builtin_amdgcn_mfma_f32_16x16x32_bf16(aw, bt[kt], ee, 0, 0, 0);
            }
            const int fb = 16 * ft + 4 * lg;
            f32x4 bb = *(const f32x4*)&s_bias[HH + fb];
            f32x4 hv = *(const f32x4*)(hrow + fb);
            if (valid) {
#pragma unroll
                for (int reg = 0; reg < 4; ++reg) {
                    float m = fmaxf(hv[reg] + ee[reg] + bb[reg], 0.f) * nrm;
                    atomicAdd(&agg[c * HH + fb + reg], m);
                }
            }
        }
    }
}

// ---------------- small elementwise kernels --------------------------------------
__global__ void deg_init_kernel(float* __restrict__ deg, int N)
{
    int i = blockIdx.x * blockDim.x + threadIdx.x;
    if (i < N) deg[i] = 1.f;
}

__global__ void deg_accum_kernel(const int* __restrict__ row, float* __restrict__ deg, int E)
{
    int e = blockIdx.x * blockDim.x + threadIdx.x;
    if (e < E) atomicAdd(&deg[row[e]], 1.f);
}

__global__ void gcn_epilogue_kernel(
    const float* __restrict__ agg, const float* __restrict__ hbuf,
    const float* __restrict__ root, const float* __restrict__ deg,
    const float* __restrict__ gamma, const float* __restrict__ beta,
    const float* __restrict__ mean, const float* __restrict__ var,
    float* __restrict__ feats, int N)
{
    int idx = blockIdx.x * blockDim.x + threadIdx.x;
    if (idx >= N * HH) return;
    int n = idx / HH, f = idx - n * HH;
    float self = fmaxf(hbuf[idx] + root[f], 0.f) / deg[n];
    float v = fmaxf(agg[idx] + self, 0.f);
    v = (v - mean[f]) * rsqrtf(var[f] + 1e-5f) * gamma[f] + beta[f];
    feats[(long)n * CAT + f] = v;
}

__global__ void gin_pre_kernel(
    const float* __restrict__ h, int h_stride,
    const float* __restrict__ agg,
    const float* __restrict__ eps_arr, int li,
    float* __restrict__ z, int N)
{
    int idx = blockIdx.x * blockDim.x + threadIdx.x;
    if (idx >= N * HH) return;
    int n = idx / HH, f = idx - n * HH;
    z[idx] = (1.f + eps_arr[li]) * h[(long)n * h_stride + f] + agg[idx];
}

__global__ void gin_post_kernel(
    const float* __restrict__ zout,
    const float* __restrict__ gamma, const float* __restrict__ beta,
    const float* __restrict__ mean, const float* __restrict__ var,
    float* __restrict__ feats, int slot, int N)
{
    int idx = blockIdx.x * blockDim.x + threadIdx.x;
    if (idx >= N * HH) return;
    int n = idx / HH, f = idx - n * HH;
    float v = fmaxf(zout[idx], 0.f);
    v = (v - mean[f]) * rsqrtf(var[f] + 1e-5f) * gamma[f] + beta[f];
    feats[(long)n * CAT + slot * HH + f] = v;
}

// ---------------- launch ----------------------------------------------------------
extern "C" void kernel_launch(void* const* d_in, const int* in_sizes, int n_in,
                              void* d_out, int out_size, void* d_ws, size_t ws_size,
                              hipStream_t stream)
{
    const float* x         = (const float*)d_in[0];
    const int*   eidx      = (const int*)d_in[1];
    const float* edge_attr = (const float*)d_in[2];
    const float* gcn_lin_w = (const float*)d_in[3];
    const float* gcn_lin_b = (const float*)d_in[4];
    const float* gcn_root  = (const float*)d_in[5];
    const float* gcn_bw1   = (const float*)d_in[6];
    const float* gcn_bb1   = (const float*)d_in[7];
    const float* gcn_bw2   = (const float*)d_in[8];
    const float* gcn_bb2   = (const float*)d_in[9];
    const float* gin_bw1   = (const float*)d_in[10];
    const float* gin_bb1   = (const float*)d_in[11];
    const float* gin_bw2   = (const float*)d_in[12];
    const float* gin_bb2   = (const float*)d_in[13];
    const float* gin_mw1   = (const float*)d_in[14];
    const float* gin_mb1   = (const float*)d_in[15];
    const float* gin_mw2   = (const float*)d_in[16];
    const float* gin_mb2   = (const float*)d_in[17];
    const float* gin_eps   = (const float*)d_in[18];
    const float* bn_gamma  = (const float*)d_in[19];
    const float* bn_beta   = (const float*)d_in[20];
    const float* bn_mean   = (const float*)d_in[21];
    const float* bn_var    = (const float*)d_in[22];
    const float* fc1_w     = (const float*)d_in[23];
    const float* fc1_b     = (const float*)d_in[24];
    const float* fc2_w     = (const float*)d_in[25];
    const float* fc2_b     = (const float*)d_in[26];
    float* out = (float*)d_out;

    const int N = in_sizes[0] / 128;   // 50000
    const int E = in_sizes[1] / 2;     // 800000
    const int* row = eidx;
    const int* col = eidx + E;

    char* ws = (char*)d_ws;
    float* deg   = (float*)ws;                               // N floats (256KB slot)
    float* hbuf  = (float*)(ws + (size_t)256 * 1024);        // N*96
    float* tmp   = hbuf + (size_t)N * HH;                    // N*96 (agg / mlp temp)
    float* feats = tmp + (size_t)N * HH;                     // N*288
    float* agg = tmp;

    const size_t nh_bytes = (size_t)N * HH * sizeof(float);
    const int ew_blocks = 1024;                              // 4/CU x 256 CU resident
    const int nh_grid = (N * HH + 255) / 256;
    const int gemm_grid = (N + 63) / 64;

    // degrees (deg = 1 + outdeg(row)); exact integer counts in f32
    deg_init_kernel<<<(N + 255) / 256, 256, 0, stream>>>(deg, N);
    deg_accum_kernel<<<(E + 255) / 256, 256, 0, stream>>>(row, deg, E);

    // ---- layer 0: GCN ----
    gemm_kernel<HH, false><<<gemm_grid, 256, 0, stream>>>(x, 128, gcn_lin_w, gcn_lin_b,
                                                          hbuf, HH, N, 128);
    hipMemsetAsync(agg, 0, nh_bytes, stream);
    edge_kernel<true><<<ew_blocks, 256, 0, stream>>>(edge_attr, row, col,
                                                     gcn_bw1, gcn_bb1, gcn_bw2, gcn_bb2,
                                                     hbuf, HH, deg, agg, E);
    gcn_epilogue_kernel<<<nh_grid, 256, 0, stream>>>(agg, hbuf, gcn_root, deg,
                                                     bn_gamma, bn_beta, bn_mean, bn_var,
                                                     feats, N);

    // ---- layers 1..2: GIN ----
    for (int i = 0; i < 2; ++i) {
        const float* h_prev = feats + i * HH;   // stride CAT
        hipMemsetAsync(agg, 0, nh_bytes, stream);
        edge_kernel<false><<<ew_blocks, 256, 0, stream>>>(
            edge_attr, row, col,
            gin_bw1 + (size_t)i * EDGEF * HH, gin_bb1 + i * HH,
            gin_bw2 + (size_t)i * HH * HH, gin_bb2 + i * HH,
            h_prev, CAT, deg, agg, E);
        gin_pre_kernel<<<nh_grid, 256, 0, stream>>>(h_prev, CAT, agg, gin_eps, i, hbuf, N);
        gemm_kernel<HH, true><<<gemm_grid, 256, 0, stream>>>(
            hbuf, HH, gin_mw1 + (size_t)i * HH * HH, gin_mb1 + i * HH, tmp, HH, N, HH);
        gemm_kernel<HH, false><<<gemm_grid, 256, 0, stream>>>(
            tmp, HH, gin_mw2 + (size_t)i * HH * HH, gin_mb2 + i * HH, hbuf, HH, N, HH);
        gin_post_kernel<<<nh_grid, 256, 0, stream>>>(
            hbuf, bn_gamma + (i + 1) * HH, bn_beta + (i + 1) * HH,
            bn_mean + (i + 1) * HH, bn_var + (i + 1) * HH, feats, i + 1, N);
    }

    // ---- head ----
    gemm_kernel<HH, true><<<gemm_grid, 256, 0, stream>>>(feats, CAT, fc1_w, fc1_b,
                                                         hbuf, HH, N, CAT);
    gemm_kernel<64, false><<<gemm_grid, 256, 0, stream>>>(hbuf, HH, fc2_w, fc2_b,
                                                          out, 64, N, HH);
}

// Round 3
// 1458.901 us; speedup vs baseline: 2.3361x; 2.3361x over previous
//
#include <hip/hip_runtime.h>

// NodeGCN: GCNConv + 2x GINConv (edge-attr MLPs) + BN + concat + 2-layer head.
// Round 3: kill the 76.8M global f32 atomics (they write through the coherence
// point at ~16B each = 1.2GB/dispatch). Build CSR-by-col once per call
// (hist -> 2-level scan -> scatter), then node-centric MFMA edge kernel:
// one wave per destination node, register accumulation, shfl_xor reduce,
// plain stores to agg. Edge MLP stays bf16 MFMA (verified layouts from R2).

#define HH 96
#define EDGEF 16
#define CAT (3 * HH)

typedef __attribute__((ext_vector_type(8))) short bf16x8;
typedef __attribute__((ext_vector_type(4))) float f32x4;

__device__ __forceinline__ short f2bf(float f) {
    unsigned u = __float_as_uint(f);
    u += 0x7fffu + ((u >> 16) & 1u);      // round-to-nearest-even
    return (short)(u >> 16);
}

// ---------------- generic tiled GEMM: C[M,F] = act(A[M,K] @ W[K,F] + b) ----------
template <int F, bool RELU>
__global__ __launch_bounds__(256) void gemm_kernel(
    const float* __restrict__ A, int lda,
    const float* __restrict__ W,
    const float* __restrict__ bias,
    float* __restrict__ C, int ldc,
    int M, int K)
{
    constexpr int BM = 64, BK = 32;
    constexpr int FPT = F / 16;
    __shared__ float As[BM][BK + 1];
    __shared__ float Ws[BK][F];

    const int tid = threadIdx.x;
    const int ty = tid >> 4, tx = tid & 15;
    const int m0 = blockIdx.x * BM;

    float acc[4][FPT];
#pragma unroll
    for (int i = 0; i < 4; ++i)
#pragma unroll
        for (int j = 0; j < FPT; ++j) acc[i][j] = 0.f;

    for (int k0 = 0; k0 < K; k0 += BK) {
        __syncthreads();
#pragma unroll
        for (int i = 0; i < (BM * BK) / 256; ++i) {
            int idx = i * 256 + tid;
            int r = idx >> 5, c = idx & 31;
            int gr = m0 + r;
            As[r][c] = (gr < M) ? A[(long)gr * lda + k0 + c] : 0.f;
        }
#pragma unroll
        for (int i = 0; i < (BK * F) / 256; ++i) {
            int idx = i * 256 + tid;
            int k = idx / F, f = idx % F;
            Ws[k][f] = W[(long)(k0 + k) * F + f];
        }
        __syncthreads();
#pragma unroll
        for (int k = 0; k < BK; ++k) {
            float a[4], w[FPT];
#pragma unroll
            for (int i = 0; i < 4; ++i) a[i] = As[ty + i * 16][k];
#pragma unroll
            for (int j = 0; j < FPT; ++j) w[j] = Ws[k][tx + j * 16];
#pragma unroll
            for (int i = 0; i < 4; ++i)
#pragma unroll
                for (int j = 0; j < FPT; ++j)
                    acc[i][j] = fmaf(a[i], w[j], acc[i][j]);
        }
    }

#pragma unroll
    for (int i = 0; i < 4; ++i) {
        int r = m0 + ty + i * 16;
        if (r < M) {
#pragma unroll
            for (int j = 0; j < FPT; ++j) {
                int f = tx + j * 16;
                float v = acc[i][j] + bias[f];
                if (RELU) v = fmaxf(v, 0.f);
                C[(long)r * ldc + f] = v;
            }
        }
    }
}

// ---------------- CSR build: hist -> scan -> scatter -----------------------------
__global__ void zero_int_kernel(int* __restrict__ p, int n)
{
    int i = blockIdx.x * blockDim.x + threadIdx.x;
    if (i < n) p[i] = 0;
}

__global__ void hist_kernel(const int* __restrict__ col, int* __restrict__ cnt, int E)
{
    int e = blockIdx.x * blockDim.x + threadIdx.x;
    if (e < E) atomicAdd(&cnt[col[e]], 1);
}

// per-256-chunk exclusive scan + chunk totals
__global__ void scan1_kernel(const int* __restrict__ cnt, int* __restrict__ start,
                             int* __restrict__ bsum, int N)
{
    __shared__ int s[256];
    int tid = threadIdx.x;
    int i = blockIdx.x * 256 + tid;
    int v = (i < N) ? cnt[i] : 0;
    s[tid] = v;
    __syncthreads();
#pragma unroll
    for (int off = 1; off < 256; off <<= 1) {
        int t = (tid >= off) ? s[tid - off] : 0;
        __syncthreads();
        s[tid] += t;
        __syncthreads();
    }
    if (i < N) start[i] = s[tid] - v;          // exclusive within chunk
    if (tid == 255) bsum[blockIdx.x] = s[255]; // chunk total
}

// single block: exclusive scan of <=256 chunk totals
__global__ void scan2_kernel(int* __restrict__ bsum, int nb)
{
    __shared__ int s[256];
    int tid = threadIdx.x;
    int v = (tid < nb) ? bsum[tid] : 0;
    s[tid] = v;
    __syncthreads();
#pragma unroll
    for (int off = 1; off < 256; off <<= 1) {
        int t = (tid >= off) ? s[tid - off] : 0;
        __syncthreads();
        s[tid] += t;
        __syncthreads();
    }
    if (tid < nb) bsum[tid] = s[tid] - v;      // exclusive chunk offsets
}

__global__ void scan3_kernel(int* __restrict__ start, const int* __restrict__ bsum,
                             int* __restrict__ cursor, int N, int E)
{
    int i = blockIdx.x * blockDim.x + threadIdx.x;
    if (i < N) {
        int f = start[i] + bsum[i >> 8];
        start[i] = f;
        cursor[i] = f;
    } else if (i == N) {
        start[N] = E;
    }
}

__global__ void scatter_kernel(const int* __restrict__ row, const int* __restrict__ col,
                               int* __restrict__ cursor,
                               int* __restrict__ edge_order, int* __restrict__ row_sorted,
                               int E)
{
    int e = blockIdx.x * blockDim.x + threadIdx.x;
    if (e < E) {
        int c = col[e];
        int p = atomicAdd(&cursor[c], 1);
        edge_order[p] = e;
        row_sorted[p] = row[e];
    }
}

// ---------------- node-centric MFMA edge kernel ----------------------------------
// One wave per destination node c; edges seg_start[c]..seg_start[c+1] in batches
// of 16. Edge MLP via mfma_f32_16x16x32_bf16 (layouts verified in R2):
//  GEMM1: t[e][f] = relu(ea@bw1+bb1)       A row=lr(edge), D row=4lg+reg(edge)
//  GEMM2: ee^T[f][e] = bw2^T @ t^T          D col=lr(edge), row=16ft+4lg+reg(feat)
// msg accumulated per-lane across batches; one shfl_xor tree over the 16-edge
// lane dim at node end; plain f32x4 stores to agg. ZERO atomics.
template <bool GCN>
__global__ __launch_bounds__(256, 4) void edge_kernel(
    const float* __restrict__ edge_attr,
    const int* __restrict__ edge_order, const int* __restrict__ row_sorted,
    const int* __restrict__ seg_start,
    const float* __restrict__ bw1, const float* __restrict__ bb1,
    const float* __restrict__ bw2, const float* __restrict__ bb2,
    const float* __restrict__ h, int h_stride,
    const float* __restrict__ deg,
    float* __restrict__ agg,
    int N)
{
    __shared__ __align__(16) short s_bw2T[96][104];  // bw2^T bf16 [f][k]
    __shared__ __align__(16) short s_t[64][104];     // t bf16 [edge][feat], wave-private rows
    __shared__ float s_bias[192];                    // bb1 | bb2

    const int tid = threadIdx.x;
    const int lane = tid & 63;
    const int w = tid >> 6;
    const int lr = lane & 15;
    const int lg = lane >> 4;

    for (int idx = tid; idx < HH * HH; idx += 256) {
        int k = idx / HH, f = idx - k * HH;
        s_bw2T[f][k] = f2bf(bw2[idx]);
    }
    if (tid < HH) { s_bias[tid] = bb1[tid]; s_bias[HH + tid] = bb2[tid]; }

    bf16x8 bwf[6];
#pragma unroll
    for (int ft = 0; ft < 6; ++ft)
#pragma unroll
        for (int j = 0; j < 8; ++j) bwf[ft][j] = 0;
    if (lg < 2) {
#pragma unroll
        for (int ft = 0; ft < 6; ++ft)
#pragma unroll
            for (int j = 0; j < 8; ++j)
                bwf[ft][j] = f2bf(bw1[(8 * lg + j) * HH + lr + 16 * ft]);
    }
    __syncthreads();

    const f32x4 zf = {0.f, 0.f, 0.f, 0.f};
    const int nwaves = gridDim.x * 4;

    for (int c = blockIdx.x * 4 + w; c < N; c += nwaves) {
        const int s0 = seg_start[c];
        const int s1 = seg_start[c + 1];
        float dinv_c = 1.f;
        if (GCN) dinv_c = rsqrtf(deg[c]);

        f32x4 acc[6];
#pragma unroll
        for (int ft = 0; ft < 6; ++ft) acc[ft] = zf;

        for (int b = s0; b < s1; b += 16) {
            const int epos = b + lr;
            const bool vld = (epos < s1);
            const int epc = vld ? epos : s0;          // clamp: finite garbage, masked later
            const int eo = edge_order[epc];
            const int r  = row_sorted[epc];

            // GEMM1 A-frag: ea[edge=lr][k=8lg+j] (k<16 real, rest zero)
            bf16x8 ae;
#pragma unroll
            for (int j = 0; j < 8; ++j) ae[j] = 0;
            if (lg < 2) {
                const float* ep = edge_attr + (size_t)eo * EDGEF + 8 * lg;
                f32x4 a0 = *(const f32x4*)ep;
                f32x4 a1 = *(const f32x4*)(ep + 4);
#pragma unroll
                for (int j = 0; j < 4; ++j) { ae[j] = f2bf(a0[j]); ae[4 + j] = f2bf(a1[j]); }
            }

            // GEMM1 + bias + relu -> s_t
#pragma unroll
            for (int ft = 0; ft < 6; ++ft) {
                f32x4 tacc = __builtin_amdgcn_mfma_f32_16x16x32_bf16(ae, bwf[ft], zf, 0, 0, 0);
                float bsv = s_bias[lr + 16 * ft];
#pragma unroll
                for (int reg = 0; reg < 4; ++reg) {
                    float v = fmaxf(tacc[reg] + bsv, 0.f);
                    s_t[16 * w + 4 * lg + reg][lr + 16 * ft] = f2bf(v);
                }
            }

            // GEMM2 B-frags: t^T, col=edge=lr
            bf16x8 bt[3];
#pragma unroll
            for (int kt = 0; kt < 3; ++kt)
                bt[kt] = *(const bf16x8*)&s_t[16 * w + lr][8 * lg + 32 * kt];

            float nrm = 1.f;
            if (GCN) nrm = rsqrtf(deg[r]) * dinv_c;
            const float* hrow = h + (size_t)r * h_stride;

#pragma unroll
            for (int ft = 0; ft < 6; ++ft) {
                f32x4 ee = zf;
#pragma unroll
                for (int kt = 0; kt < 3; ++kt) {
                    bf16x8 aw = *(const bf16x8*)&s_bw2T[lr + 16 * ft][8 * lg + 32 * kt];
                    ee = __builtin_amdgcn_mfma_f32_16x16x32_bf16(aw, bt[kt], ee, 0, 0, 0);
                }
                const int fb = 16 * ft + 4 * lg;
                f32x4 bb = *(const f32x4*)&s_bias[HH + fb];
                f32x4 hv = *(const f32x4*)(hrow + fb);
#pragma unroll
                for (int reg = 0; reg < 4; ++reg) {
                    float m = fmaxf(hv[reg] + ee[reg] + bb[reg], 0.f) * nrm;
                    acc[ft][reg] += vld ? m : 0.f;
                }
            }
        }

        // reduce over the 16-edge lane dimension (bits 0..3 of lane id)
#pragma unroll
        for (int ft = 0; ft < 6; ++ft) {
#pragma unroll
            for (int reg = 0; reg < 4; ++reg) {
                float v = acc[ft][reg];
                v += __shfl_xor(v, 1);
                v += __shfl_xor(v, 2);
                v += __shfl_xor(v, 4);
                v += __shfl_xor(v, 8);
                acc[ft][reg] = v;
            }
        }
        if (lr == 0) {
#pragma unroll
            for (int ft = 0; ft < 6; ++ft)
                *(f32x4*)&agg[(size_t)c * HH + 16 * ft + 4 * lg] = acc[ft];
        }
    }
}

// ---------------- small elementwise kernels --------------------------------------
__global__ void deg_init_kernel(float* __restrict__ deg, int N)
{
    int i = blockIdx.x * blockDim.x + threadIdx.x;
    if (i < N) deg[i] = 1.f;
}

__global__ void deg_accum_kernel(const int* __restrict__ row, float* __restrict__ deg, int E)
{
    int e = blockIdx.x * blockDim.x + threadIdx.x;
    if (e < E) atomicAdd(&deg[row[e]], 1.f);
}

__global__ void gcn_epilogue_kernel(
    const float* __restrict__ agg, const float* __restrict__ hbuf,
    const float* __restrict__ root, const float* __restrict__ deg,
    const float* __restrict__ gamma, const float* __restrict__ beta,
    const float* __restrict__ mean, const float* __restrict__ var,
    float* __restrict__ feats, int N)
{
    int idx = blockIdx.x * blockDim.x + threadIdx.x;
    if (idx >= N * HH) return;
    int n = idx / HH, f = idx - n * HH;
    float self = fmaxf(hbuf[idx] + root[f], 0.f) / deg[n];
    float v = fmaxf(agg[idx] + self, 0.f);
    v = (v - mean[f]) * rsqrtf(var[f] + 1e-5f) * gamma[f] + beta[f];
    feats[(long)n * CAT + f] = v;
}

__global__ void gin_pre_kernel(
    const float* __restrict__ h, int h_stride,
    const float* __restrict__ agg,
    const float* __restrict__ eps_arr, int li,
    float* __restrict__ z, int N)
{
    int idx = blockIdx.x * blockDim.x + threadIdx.x;
    if (idx >= N * HH) return;
    int n = idx / HH, f = idx - n * HH;
    z[idx] = (1.f + eps_arr[li]) * h[(long)n * h_stride + f] + agg[idx];
}

__global__ void gin_post_kernel(
    const float* __restrict__ zout,
    const float* __restrict__ gamma, const float* __restrict__ beta,
    const float* __restrict__ mean, const float* __restrict__ var,
    float* __restrict__ feats, int slot, int N)
{
    int idx = blockIdx.x * blockDim.x + threadIdx.x;
    if (idx >= N * HH) return;
    int n = idx / HH, f = idx - n * HH;
    float v = fmaxf(zout[idx], 0.f);
    v = (v - mean[f]) * rsqrtf(var[f] + 1e-5f) * gamma[f] + beta[f];
    feats[(long)n * CAT + slot * HH + f] = v;
}

// ---------------- launch ----------------------------------------------------------
extern "C" void kernel_launch(void* const* d_in, const int* in_sizes, int n_in,
                              void* d_out, int out_size, void* d_ws, size_t ws_size,
                              hipStream_t stream)
{
    const float* x         = (const float*)d_in[0];
    const int*   eidx      = (const int*)d_in[1];
    const float* edge_attr = (const float*)d_in[2];
    const float* gcn_lin_w = (const float*)d_in[3];
    const float* gcn_lin_b = (const float*)d_in[4];
    const float* gcn_root  = (const float*)d_in[5];
    const float* gcn_bw1   = (const float*)d_in[6];
    const float* gcn_bb1   = (const float*)d_in[7];
    const float* gcn_bw2   = (const float*)d_in[8];
    const float* gcn_bb2   = (const float*)d_in[9];
    const float* gin_bw1   = (const float*)d_in[10];
    const float* gin_bb1   = (const float*)d_in[11];
    const float* gin_bw2   = (const float*)d_in[12];
    const float* gin_bb2   = (const float*)d_in[13];
    const float* gin_mw1   = (const float*)d_in[14];
    const float* gin_mb1   = (const float*)d_in[15];
    const float* gin_mw2   = (const float*)d_in[16];
    const float* gin_mb2   = (const float*)d_in[17];
    const float* gin_eps   = (const float*)d_in[18];
    const float* bn_gamma  = (const float*)d_in[19];
    const float* bn_beta   = (const float*)d_in[20];
    const float* bn_mean   = (const float*)d_in[21];
    const float* bn_var    = (const float*)d_in[22];
    const float* fc1_w     = (const float*)d_in[23];
    const float* fc1_b     = (const float*)d_in[24];
    const float* fc2_w     = (const float*)d_in[25];
    const float* fc2_b     = (const float*)d_in[26];
    float* out = (float*)d_out;

    const int N = in_sizes[0] / 128;   // 50000
    const int E = in_sizes[1] / 2;     // 800000
    const int* row = eidx;
    const int* col = eidx + E;

    // ws layout (bytes)
    char* ws = (char*)d_ws;
    float* deg        = (float*)(ws);                        // N f32
    int*   seg_start  = (int*)(ws + (size_t)256 * 1024);     // N+1
    int*   cursor     = (int*)(ws + (size_t)512 * 1024);     // N (also hist cnt)
    int*   bsum       = (int*)(ws + (size_t)768 * 1024);     // 256
    int*   edge_order = (int*)(ws + (size_t)1024 * 1024);    // E
    int*   row_sorted = edge_order + E;                      // E
    float* hbuf  = (float*)(ws + (size_t)8 * 1024 * 1024);   // N*96
    float* tmp   = hbuf + (size_t)N * HH;                    // N*96
    float* feats = tmp + (size_t)N * HH;                     // N*288
    float* agg = tmp;

    const int ew_blocks = 1024;
    const int nh_grid = (N * HH + 255) / 256;
    const int gemm_grid = (N + 63) / 64;
    const int e_grid = (E + 255) / 256;
    const int n_grid = (N + 255) / 256;
    const int nchunks = (N + 255) / 256;                     // 196

    // ---- degrees + CSR build (once per call) ----
    deg_init_kernel<<<n_grid, 256, 0, stream>>>(deg, N);
    deg_accum_kernel<<<e_grid, 256, 0, stream>>>(row, deg, E);
    zero_int_kernel<<<n_grid, 256, 0, stream>>>(cursor, N);
    hist_kernel<<<e_grid, 256, 0, stream>>>(col, cursor, E);
    scan1_kernel<<<nchunks, 256, 0, stream>>>(cursor, seg_start, bsum, N);
    scan2_kernel<<<1, 256, 0, stream>>>(bsum, nchunks);
    scan3_kernel<<<(N + 256) / 256, 256, 0, stream>>>(seg_start, bsum, cursor, N, E);
    scatter_kernel<<<e_grid, 256, 0, stream>>>(row, col, cursor, edge_order, row_sorted, E);

    // ---- layer 0: GCN ----
    gemm_kernel<HH, false><<<gemm_grid, 256, 0, stream>>>(x, 128, gcn_lin_w, gcn_lin_b,
                                                          hbuf, HH, N, 128);
    edge_kernel<true><<<ew_blocks, 256, 0, stream>>>(edge_attr, edge_order, row_sorted,
                                                     seg_start,
                                                     gcn_bw1, gcn_bb1, gcn_bw2, gcn_bb2,
                                                     hbuf, HH, deg, agg, N);
    gcn_epilogue_kernel<<<nh_grid, 256, 0, stream>>>(agg, hbuf, gcn_root, deg,
                                                     bn_gamma, bn_beta, bn_mean, bn_var,
                                                     feats, N);

    // ---- layers 1..2: GIN ----
    for (int i = 0; i < 2; ++i) {
        const float* h_prev = feats + i * HH;   // stride CAT
        edge_kernel<false><<<ew_blocks, 256, 0, stream>>>(
            edge_attr, edge_order, row_sorted, seg_start,
            gin_bw1 + (size_t)i * EDGEF * HH, gin_bb1 + i * HH,
            gin_bw2 + (size_t)i * HH * HH, gin_bb2 + i * HH,
            h_prev, CAT, deg, agg, N);
        gin_pre_kernel<<<nh_grid, 256, 0, stream>>>(h_prev, CAT, agg, gin_eps, i, hbuf, N);
        gemm_kernel<HH, true><<<gemm_grid, 256, 0, stream>>>(
            hbuf, HH, gin_mw1 + (size_t)i * HH * HH, gin_mb1 + i * HH, tmp, HH, N, HH);
        gemm_kernel<HH, false><<<gemm_grid, 256, 0, stream>>>(
            tmp, HH, gin_mw2 + (size_t)i * HH * HH, gin_mb2 + i * HH, hbuf, HH, N, HH);
        gin_post_kernel<<<nh_grid, 256, 0, stream>>>(
            hbuf, bn_gamma + (i + 1) * HH, bn_beta + (i + 1) * HH,
            bn_mean + (i + 1) * HH, bn_var + (i + 1) * HH, feats, i + 1, N);
    }

    // ---- head ----
    gemm_kernel<HH, true><<<gemm_grid, 256, 0, stream>>>(feats, CAT, fc1_w, fc1_b,
                                                         hbuf, HH, N, CAT);
    gemm_kernel<64, false><<<gemm_grid, 256, 0, stream>>>(hbuf, HH, fc2_w, fc2_b,
                                                          out, 64, N, HH);
}

// Round 4
// 1406.889 us; speedup vs baseline: 2.4224x; 1.0370x over previous
//
#include <hip/hip_runtime.h>

// NodeGCN: GCNConv + 2x GINConv (edge-attr MLPs) + BN + concat + 2-layer head.
// Round 4: edge kernel traffic diet. (1) edge_attr pre-permuted to CSR order in
// bf16 (sequential 16B loads, no indirection), (2) h gathered as bf16 (192B/row
// vs 384B), (3) fewer live temps (spill relief). CSR build + node-centric MFMA
// edge kernel (no atomics) as in R3.

#define HH 96
#define EDGEF 16
#define CAT (3 * HH)

typedef __attribute__((ext_vector_type(8))) short bf16x8;
typedef __attribute__((ext_vector_type(4))) float f32x4;
typedef __attribute__((ext_vector_type(4))) unsigned short ubf16x4;

__device__ __forceinline__ unsigned short f2bf(float f) {
    unsigned u = __float_as_uint(f);
    u += 0x7fffu + ((u >> 16) & 1u);      // round-to-nearest-even
    return (unsigned short)(u >> 16);
}
__device__ __forceinline__ float bf2f(unsigned short s) {
    return __uint_as_float(((unsigned)s) << 16);
}

// ---------------- generic tiled GEMM: C[M,F] = act(A[M,K] @ W[K,F] + b) ----------
template <int F, bool RELU>
__global__ __launch_bounds__(256) void gemm_kernel(
    const float* __restrict__ A, int lda,
    const float* __restrict__ W,
    const float* __restrict__ bias,
    float* __restrict__ C, int ldc,
    int M, int K)
{
    constexpr int BM = 64, BK = 32;
    constexpr int FPT = F / 16;
    __shared__ float As[BM][BK + 1];
    __shared__ float Ws[BK][F];

    const int tid = threadIdx.x;
    const int ty = tid >> 4, tx = tid & 15;
    const int m0 = blockIdx.x * BM;

    float acc[4][FPT];
#pragma unroll
    for (int i = 0; i < 4; ++i)
#pragma unroll
        for (int j = 0; j < FPT; ++j) acc[i][j] = 0.f;

    for (int k0 = 0; k0 < K; k0 += BK) {
        __syncthreads();
#pragma unroll
        for (int i = 0; i < (BM * BK) / 256; ++i) {
            int idx = i * 256 + tid;
            int r = idx >> 5, c = idx & 31;
            int gr = m0 + r;
            As[r][c] = (gr < M) ? A[(long)gr * lda + k0 + c] : 0.f;
        }
#pragma unroll
        for (int i = 0; i < (BK * F) / 256; ++i) {
            int idx = i * 256 + tid;
            int k = idx / F, f = idx % F;
            Ws[k][f] = W[(long)(k0 + k) * F + f];
        }
        __syncthreads();
#pragma unroll
        for (int k = 0; k < BK; ++k) {
            float a[4], w[FPT];
#pragma unroll
            for (int i = 0; i < 4; ++i) a[i] = As[ty + i * 16][k];
#pragma unroll
            for (int j = 0; j < FPT; ++j) w[j] = Ws[k][tx + j * 16];
#pragma unroll
            for (int i = 0; i < 4; ++i)
#pragma unroll
                for (int j = 0; j < FPT; ++j)
                    acc[i][j] = fmaf(a[i], w[j], acc[i][j]);
        }
    }

#pragma unroll
    for (int i = 0; i < 4; ++i) {
        int r = m0 + ty + i * 16;
        if (r < M) {
#pragma unroll
            for (int j = 0; j < FPT; ++j) {
                int f = tx + j * 16;
                float v = acc[i][j] + bias[f];
                if (RELU) v = fmaxf(v, 0.f);
                C[(long)r * ldc + f] = v;
            }
        }
    }
}

// ---------------- CSR build: hist -> scan -> scatter -----------------------------
__global__ void zero_int_kernel(int* __restrict__ p, int n)
{
    int i = blockIdx.x * blockDim.x + threadIdx.x;
    if (i < n) p[i] = 0;
}

__global__ void hist_kernel(const int* __restrict__ col, int* __restrict__ cnt, int E)
{
    int e = blockIdx.x * blockDim.x + threadIdx.x;
    if (e < E) atomicAdd(&cnt[col[e]], 1);
}

__global__ void scan1_kernel(const int* __restrict__ cnt, int* __restrict__ start,
                             int* __restrict__ bsum, int N)
{
    __shared__ int s[256];
    int tid = threadIdx.x;
    int i = blockIdx.x * 256 + tid;
    int v = (i < N) ? cnt[i] : 0;
    s[tid] = v;
    __syncthreads();
#pragma unroll
    for (int off = 1; off < 256; off <<= 1) {
        int t = (tid >= off) ? s[tid - off] : 0;
        __syncthreads();
        s[tid] += t;
        __syncthreads();
    }
    if (i < N) start[i] = s[tid] - v;
    if (tid == 255) bsum[blockIdx.x] = s[255];
}

__global__ void scan2_kernel(int* __restrict__ bsum, int nb)
{
    __shared__ int s[256];
    int tid = threadIdx.x;
    int v = (tid < nb) ? bsum[tid] : 0;
    s[tid] = v;
    __syncthreads();
#pragma unroll
    for (int off = 1; off < 256; off <<= 1) {
        int t = (tid >= off) ? s[tid - off] : 0;
        __syncthreads();
        s[tid] += t;
        __syncthreads();
    }
    if (tid < nb) bsum[tid] = s[tid] - v;
}

__global__ void scan3_kernel(int* __restrict__ start, const int* __restrict__ bsum,
                             int* __restrict__ cursor, int N, int E)
{
    int i = blockIdx.x * blockDim.x + threadIdx.x;
    if (i < N) {
        int f = start[i] + bsum[i >> 8];
        start[i] = f;
        cursor[i] = f;
    } else if (i == N) {
        start[N] = E;
    }
}

__global__ void scatter_kernel(const int* __restrict__ row, const int* __restrict__ col,
                               int* __restrict__ cursor,
                               int* __restrict__ edge_order, int* __restrict__ row_sorted,
                               int E)
{
    int e = blockIdx.x * blockDim.x + threadIdx.x;
    if (e < E) {
        int c = col[e];
        int p = atomicAdd(&cursor[c], 1);
        edge_order[p] = e;
        row_sorted[p] = row[e];
    }
}

// permute edge_attr into CSR order, f32 -> bf16 (32B/edge, sequential writes)
__global__ void permute_ea_kernel(const float* __restrict__ ea,
                                  const int* __restrict__ edge_order,
                                  unsigned short* __restrict__ eas, int E)
{
    int p = blockIdx.x * blockDim.x + threadIdx.x;
    if (p >= E) return;
    const float* src = ea + (size_t)edge_order[p] * EDGEF;
    f32x4 v0 = *(const f32x4*)(src);
    f32x4 v1 = *(const f32x4*)(src + 4);
    f32x4 v2 = *(const f32x4*)(src + 8);
    f32x4 v3 = *(const f32x4*)(src + 12);
    bf16x8 o0, o1;
#pragma unroll
    for (int j = 0; j < 4; ++j) {
        o0[j] = (short)f2bf(v0[j]); o0[4 + j] = (short)f2bf(v1[j]);
        o1[j] = (short)f2bf(v2[j]); o1[4 + j] = (short)f2bf(v3[j]);
    }
    *(bf16x8*)(eas + (size_t)p * EDGEF) = o0;
    *(bf16x8*)(eas + (size_t)p * EDGEF + 8) = o1;
}

// h (f32, strided) -> hbf (bf16, dense [N][96])
__global__ void h2bf_kernel(const float* __restrict__ h, int h_stride,
                            unsigned short* __restrict__ hbf, int N)
{
    int idx = blockIdx.x * blockDim.x + threadIdx.x;    // quad index
    if (idx >= N * (HH / 4)) return;
    int n = idx / (HH / 4), q = idx - n * (HH / 4);
    f32x4 v = *(const f32x4*)(h + (size_t)n * h_stride + 4 * q);
    ubf16x4 o;
#pragma unroll
    for (int j = 0; j < 4; ++j) o[j] = f2bf(v[j]);
    *(ubf16x4*)(hbf + (size_t)n * HH + 4 * q) = o;
}

// ---------------- node-centric MFMA edge kernel ----------------------------------
// One wave per destination node c. ea_sorted is pre-permuted bf16 (sequential);
// h gathered as bf16. Register accumulation + shfl_xor reduce, plain stores.
template <bool GCN>
__global__ __launch_bounds__(256, 4) void edge_kernel(
    const unsigned short* __restrict__ ea_sorted,
    const int* __restrict__ row_sorted,
    const int* __restrict__ seg_start,
    const float* __restrict__ bw1, const float* __restrict__ bb1,
    const float* __restrict__ bw2, const float* __restrict__ bb2,
    const unsigned short* __restrict__ hbf,
    const float* __restrict__ deg,
    float* __restrict__ agg,
    int N)
{
    __shared__ __align__(16) short s_bw2T[96][104];  // bw2^T bf16 [f][k]
    __shared__ __align__(16) short s_t[64][104];     // t bf16 [edge][feat], wave-private
    __shared__ float s_bias[192];                    // bb1 | bb2

    const int tid = threadIdx.x;
    const int lane = tid & 63;
    const int w = tid >> 6;
    const int lr = lane & 15;
    const int lg = lane >> 4;

    for (int idx = tid; idx < HH * HH; idx += 256) {
        int k = idx / HH, f = idx - k * HH;
        s_bw2T[f][k] = (short)f2bf(bw2[idx]);
    }
    if (tid < HH) { s_bias[tid] = bb1[tid]; s_bias[HH + tid] = bb2[tid]; }

    bf16x8 bwf[6];
#pragma unroll
    for (int ft = 0; ft < 6; ++ft)
#pragma unroll
        for (int j = 0; j < 8; ++j) bwf[ft][j] = 0;
    if (lg < 2) {
#pragma unroll
        for (int ft = 0; ft < 6; ++ft)
#pragma unroll
            for (int j = 0; j < 8; ++j)
                bwf[ft][j] = (short)f2bf(bw1[(8 * lg + j) * HH + lr + 16 * ft]);
    }
    __syncthreads();

    const f32x4 zf = {0.f, 0.f, 0.f, 0.f};
    const int nwaves = gridDim.x * 4;

    for (int c = blockIdx.x * 4 + w; c < N; c += nwaves) {
        const int s0 = seg_start[c];
        const int s1 = seg_start[c + 1];
        float dinv_c = 1.f;
        if (GCN) dinv_c = rsqrtf(deg[c]);

        f32x4 acc[6];
#pragma unroll
        for (int ft = 0; ft < 6; ++ft) acc[ft] = zf;

        for (int b = s0; b < s1; b += 16) {
            const int epos = b + lr;
            const bool vld = (epos < s1);
            const int epc = vld ? epos : s0;
            const int r = row_sorted[epc];

            // A-frag: one sequential 16B bf16 load (k<16 real, rest zero)
            bf16x8 ae;
#pragma unroll
            for (int j = 0; j < 8; ++j) ae[j] = 0;
            if (lg < 2)
                ae = *(const bf16x8*)(ea_sorted + (size_t)epc * EDGEF + 8 * lg);

            // GEMM1 + bias + relu -> s_t
#pragma unroll
            for (int ft = 0; ft < 6; ++ft) {
                f32x4 tacc = __builtin_amdgcn_mfma_f32_16x16x32_bf16(ae, bwf[ft], zf, 0, 0, 0);
                float bsv = s_bias[lr + 16 * ft];
#pragma unroll
                for (int reg = 0; reg < 4; ++reg) {
                    float v = fmaxf(tacc[reg] + bsv, 0.f);
                    s_t[16 * w + 4 * lg + reg][lr + 16 * ft] = (short)f2bf(v);
                }
            }

            // GEMM2 B-frags: t^T, col=edge=lr
            bf16x8 bt[3];
#pragma unroll
            for (int kt = 0; kt < 3; ++kt)
                bt[kt] = *(const bf16x8*)&s_t[16 * w + lr][8 * lg + 32 * kt];

            float nrm = 1.f;
            if (GCN) nrm = rsqrtf(deg[r]) * dinv_c;
            const unsigned short* hrow = hbf + (size_t)r * HH;

#pragma unroll
            for (int ft = 0; ft < 6; ++ft) {
                f32x4 ee = zf;
#pragma unroll
                for (int kt = 0; kt < 3; ++kt) {
                    bf16x8 aw = *(const bf16x8*)&s_bw2T[lr + 16 * ft][8 * lg + 32 * kt];
                    ee = __builtin_amdgcn_mfma_f32_16x16x32_bf16(aw, bt[kt], ee, 0, 0, 0);
                }
                const int fb = 16 * ft + 4 * lg;
                f32x4 bb = *(const f32x4*)&s_bias[HH + fb];
                ubf16x4 hv = *(const ubf16x4*)(hrow + fb);   // 8B gather
#pragma unroll
                for (int reg = 0; reg < 4; ++reg) {
                    float m = fmaxf(bf2f(hv[reg]) + ee[reg] + bb[reg], 0.f) * nrm;
                    acc[ft][reg] += vld ? m : 0.f;
                }
            }
        }

        // reduce over the 16-edge lane dimension
#pragma unroll
        for (int ft = 0; ft < 6; ++ft) {
#pragma unroll
            for (int reg = 0; reg < 4; ++reg) {
                float v = acc[ft][reg];
                v += __shfl_xor(v, 1);
                v += __shfl_xor(v, 2);
                v += __shfl_xor(v, 4);
                v += __shfl_xor(v, 8);
                acc[ft][reg] = v;
            }
        }
        if (lr == 0) {
#pragma unroll
            for (int ft = 0; ft < 6; ++ft)
                *(f32x4*)&agg[(size_t)c * HH + 16 * ft + 4 * lg] = acc[ft];
        }
    }
}

// ---------------- small elementwise kernels --------------------------------------
__global__ void deg_init_kernel(float* __restrict__ deg, int N)
{
    int i = blockIdx.x * blockDim.x + threadIdx.x;
    if (i < N) deg[i] = 1.f;
}

__global__ void deg_accum_kernel(const int* __restrict__ row, float* __restrict__ deg, int E)
{
    int e = blockIdx.x * blockDim.x + threadIdx.x;
    if (e < E) atomicAdd(&deg[row[e]], 1.f);
}

__global__ void gcn_epilogue_kernel(
    const float* __restrict__ agg, const float* __restrict__ hbuf,
    const float* __restrict__ root, const float* __restrict__ deg,
    const float* __restrict__ gamma, const float* __restrict__ beta,
    const float* __restrict__ mean, const float* __restrict__ var,
    float* __restrict__ feats, int N)
{
    int idx = blockIdx.x * blockDim.x + threadIdx.x;
    if (idx >= N * HH) return;
    int n = idx / HH, f = idx - n * HH;
    float self = fmaxf(hbuf[idx] + root[f], 0.f) / deg[n];
    float v = fmaxf(agg[idx] + self, 0.f);
    v = (v - mean[f]) * rsqrtf(var[f] + 1e-5f) * gamma[f] + beta[f];
    feats[(long)n * CAT + f] = v;
}

__global__ void gin_pre_kernel(
    const float* __restrict__ h, int h_stride,
    const float* __restrict__ agg,
    const float* __restrict__ eps_arr, int li,
    float* __restrict__ z, int N)
{
    int idx = blockIdx.x * blockDim.x + threadIdx.x;
    if (idx >= N * HH) return;
    int n = idx / HH, f = idx - n * HH;
    z[idx] = (1.f + eps_arr[li]) * h[(long)n * h_stride + f] + agg[idx];
}

__global__ void gin_post_kernel(
    const float* __restrict__ zout,
    const float* __restrict__ gamma, const float* __restrict__ beta,
    const float* __restrict__ mean, const float* __restrict__ var,
    float* __restrict__ feats, int slot, int N)
{
    int idx = blockIdx.x * blockDim.x + threadIdx.x;
    if (idx >= N * HH) return;
    int n = idx / HH, f = idx - n * HH;
    float v = fmaxf(zout[idx], 0.f);
    v = (v - mean[f]) * rsqrtf(var[f] + 1e-5f) * gamma[f] + beta[f];
    feats[(long)n * CAT + slot * HH + f] = v;
}

// ---------------- launch ----------------------------------------------------------
extern "C" void kernel_launch(void* const* d_in, const int* in_sizes, int n_in,
                              void* d_out, int out_size, void* d_ws, size_t ws_size,
                              hipStream_t stream)
{
    const float* x         = (const float*)d_in[0];
    const int*   eidx      = (const int*)d_in[1];
    const float* edge_attr = (const float*)d_in[2];
    const float* gcn_lin_w = (const float*)d_in[3];
    const float* gcn_lin_b = (const float*)d_in[4];
    const float* gcn_root  = (const float*)d_in[5];
    const float* gcn_bw1   = (const float*)d_in[6];
    const float* gcn_bb1   = (const float*)d_in[7];
    const float* gcn_bw2   = (const float*)d_in[8];
    const float* gcn_bb2   = (const float*)d_in[9];
    const float* gin_bw1   = (const float*)d_in[10];
    const float* gin_bb1   = (const float*)d_in[11];
    const float* gin_bw2   = (const float*)d_in[12];
    const float* gin_bb2   = (const float*)d_in[13];
    const float* gin_mw1   = (const float*)d_in[14];
    const float* gin_mb1   = (const float*)d_in[15];
    const float* gin_mw2   = (const float*)d_in[16];
    const float* gin_mb2   = (const float*)d_in[17];
    const float* gin_eps   = (const float*)d_in[18];
    const float* bn_gamma  = (const float*)d_in[19];
    const float* bn_beta   = (const float*)d_in[20];
    const float* bn_mean   = (const float*)d_in[21];
    const float* bn_var    = (const float*)d_in[22];
    const float* fc1_w     = (const float*)d_in[23];
    const float* fc1_b     = (const float*)d_in[24];
    const float* fc2_w     = (const float*)d_in[25];
    const float* fc2_b     = (const float*)d_in[26];
    float* out = (float*)d_out;

    const int N = in_sizes[0] / 128;   // 50000
    const int E = in_sizes[1] / 2;     // 800000
    const int* row = eidx;
    const int* col = eidx + E;

    // ws layout (bytes)
    char* ws = (char*)d_ws;
    float* deg        = (float*)(ws);                        // N f32
    int*   seg_start  = (int*)(ws + (size_t)256 * 1024);     // N+1
    int*   cursor     = (int*)(ws + (size_t)512 * 1024);     // N
    int*   bsum       = (int*)(ws + (size_t)768 * 1024);     // 256
    int*   edge_order = (int*)(ws + (size_t)1024 * 1024);    // E
    int*   row_sorted = edge_order + E;                      // E          (~7.4MB end)
    unsigned short* ea_sorted = (unsigned short*)(ws + (size_t)8 * 1024 * 1024);   // E*16 bf16 (25.6MB)
    unsigned short* hbf = (unsigned short*)(ws + (size_t)34 * 1024 * 1024);        // N*96 bf16 (9.6MB)
    float* hbuf  = (float*)(ws + (size_t)44 * 1024 * 1024);  // N*96 f32
    float* tmp   = hbuf + (size_t)N * HH;                    // N*96
    float* feats = tmp + (size_t)N * HH;                     // N*288 (ends ~141MB)
    float* agg = tmp;

    const int ew_blocks = 1024;
    const int nh_grid = (N * HH + 255) / 256;
    const int q_grid = (N * (HH / 4) + 255) / 256;
    const int gemm_grid = (N + 63) / 64;
    const int e_grid = (E + 255) / 256;
    const int n_grid = (N + 255) / 256;
    const int nchunks = (N + 255) / 256;

    // ---- degrees + CSR build (once per call) ----
    deg_init_kernel<<<n_grid, 256, 0, stream>>>(deg, N);
    deg_accum_kernel<<<e_grid, 256, 0, stream>>>(row, deg, E);
    zero_int_kernel<<<n_grid, 256, 0, stream>>>(cursor, N);
    hist_kernel<<<e_grid, 256, 0, stream>>>(col, cursor, E);
    scan1_kernel<<<nchunks, 256, 0, stream>>>(cursor, seg_start, bsum, N);
    scan2_kernel<<<1, 256, 0, stream>>>(bsum, nchunks);
    scan3_kernel<<<(N + 256) / 256, 256, 0, stream>>>(seg_start, bsum, cursor, N, E);
    scatter_kernel<<<e_grid, 256, 0, stream>>>(row, col, cursor, edge_order, row_sorted, E);
    permute_ea_kernel<<<e_grid, 256, 0, stream>>>(edge_attr, edge_order, ea_sorted, E);

    // ---- layer 0: GCN ----
    gemm_kernel<HH, false><<<gemm_grid, 256, 0, stream>>>(x, 128, gcn_lin_w, gcn_lin_b,
                                                          hbuf, HH, N, 128);
    h2bf_kernel<<<q_grid, 256, 0, stream>>>(hbuf, HH, hbf, N);
    edge_kernel<true><<<ew_blocks, 256, 0, stream>>>(ea_sorted, row_sorted, seg_start,
                                                     gcn_bw1, gcn_bb1, gcn_bw2, gcn_bb2,
                                                     hbf, deg, agg, N);
    gcn_epilogue_kernel<<<nh_grid, 256, 0, stream>>>(agg, hbuf, gcn_root, deg,
                                                     bn_gamma, bn_beta, bn_mean, bn_var,
                                                     feats, N);

    // ---- layers 1..2: GIN ----
    for (int i = 0; i < 2; ++i) {
        const float* h_prev = feats + i * HH;   // stride CAT
        h2bf_kernel<<<q_grid, 256, 0, stream>>>(h_prev, CAT, hbf, N);
        edge_kernel<false><<<ew_blocks, 256, 0, stream>>>(
            ea_sorted, row_sorted, seg_start,
            gin_bw1 + (size_t)i * EDGEF * HH, gin_bb1 + i * HH,
            gin_bw2 + (size_t)i * HH * HH, gin_bb2 + i * HH,
            hbf, deg, agg, N);
        gin_pre_kernel<<<nh_grid, 256, 0, stream>>>(h_prev, CAT, agg, gin_eps, i, hbuf, N);
        gemm_kernel<HH, true><<<gemm_grid, 256, 0, stream>>>(
            hbuf, HH, gin_mw1 + (size_t)i * HH * HH, gin_mb1 + i * HH, tmp, HH, N, HH);
        gemm_kernel<HH, false><<<gemm_grid, 256, 0, stream>>>(
            tmp, HH, gin_mw2 + (size_t)i * HH * HH, gin_mb2 + i * HH, hbuf, HH, N, HH);
        gin_post_kernel<<<nh_grid, 256, 0, stream>>>(
            hbuf, bn_gamma + (i + 1) * HH, bn_beta + (i + 1) * HH,
            bn_mean + (i + 1) * HH, bn_var + (i + 1) * HH, feats, i + 1, N);
    }

    // ---- head ----
    gemm_kernel<HH, true><<<gemm_grid, 256, 0, stream>>>(feats, CAT, fc1_w, fc1_b,
                                                         hbuf, HH, N, CAT);
    gemm_kernel<64, false><<<gemm_grid, 256, 0, stream>>>(hbuf, HH, fc2_w, fc2_b,
                                                          out, 64, N, HH);
}

// Round 5
// 864.918 us; speedup vs baseline: 3.9404x; 1.6266x over previous
//
#include <hip/hip_runtime.h>

// NodeGCN: GCNConv + 2x GINConv (edge-attr MLPs) + BN + concat + 2-layer head.
// Round 5: (1) h-row staged once per edge via LDS (192B sequential per edge vs
// ~800B of scattered 32B chunks), prefetch-at-batch-start into regs, parked in
// the freed s_t slice; (2) bw1 frags from LDS (frees 24 persistent VGPRs,
// spill probe); (3) h2bf/gin_pre fused into GEMM epilogues/prologues.

#define HH 96
#define EDGEF 16
#define CAT (3 * HH)

typedef __attribute__((ext_vector_type(8))) short bf16x8;
typedef __attribute__((ext_vector_type(4))) float f32x4;
typedef __attribute__((ext_vector_type(4))) unsigned short ubf16x4;

__device__ __forceinline__ unsigned short f2bf(float f) {
    unsigned u = __float_as_uint(f);
    u += 0x7fffu + ((u >> 16) & 1u);      // round-to-nearest-even
    return (unsigned short)(u >> 16);
}
__device__ __forceinline__ float bf2f(unsigned short s) {
    return __uint_as_float(((unsigned)s) << 16);
}

// ---------------- generic tiled GEMM: C[M,F] = act(A[M,K] @ W[K,F] + b) ----------
// BFOUT: also emit bf16 copy of C (dense [M][F]) for the edge kernel's h table.
template <int F, bool RELU, bool BFOUT>
__global__ __launch_bounds__(256) void gemm_kernel(
    const float* __restrict__ A, int lda,
    const float* __restrict__ W,
    const float* __restrict__ bias,
    float* __restrict__ C, int ldc,
    unsigned short* __restrict__ hbf_out,
    int M, int K)
{
    constexpr int BM = 64, BK = 32;
    constexpr int FPT = F / 16;
    __shared__ float As[BM][BK + 1];
    __shared__ float Ws[BK][F];

    const int tid = threadIdx.x;
    const int ty = tid >> 4, tx = tid & 15;
    const int m0 = blockIdx.x * BM;

    float acc[4][FPT];
#pragma unroll
    for (int i = 0; i < 4; ++i)
#pragma unroll
        for (int j = 0; j < FPT; ++j) acc[i][j] = 0.f;

    for (int k0 = 0; k0 < K; k0 += BK) {
        __syncthreads();
#pragma unroll
        for (int i = 0; i < (BM * BK) / 256; ++i) {
            int idx = i * 256 + tid;
            int r = idx >> 5, c = idx & 31;
            int gr = m0 + r;
            As[r][c] = (gr < M) ? A[(long)gr * lda + k0 + c] : 0.f;
        }
#pragma unroll
        for (int i = 0; i < (BK * F) / 256; ++i) {
            int idx = i * 256 + tid;
            int k = idx / F, f = idx % F;
            Ws[k][f] = W[(long)(k0 + k) * F + f];
        }
        __syncthreads();
#pragma unroll
        for (int k = 0; k < BK; ++k) {
            float a[4], w[FPT];
#pragma unroll
            for (int i = 0; i < 4; ++i) a[i] = As[ty + i * 16][k];
#pragma unroll
            for (int j = 0; j < FPT; ++j) w[j] = Ws[k][tx + j * 16];
#pragma unroll
            for (int i = 0; i < 4; ++i)
#pragma unroll
                for (int j = 0; j < FPT; ++j)
                    acc[i][j] = fmaf(a[i], w[j], acc[i][j]);
        }
    }

#pragma unroll
    for (int i = 0; i < 4; ++i) {
        int r = m0 + ty + i * 16;
        if (r < M) {
#pragma unroll
            for (int j = 0; j < FPT; ++j) {
                int f = tx + j * 16;
                float v = acc[i][j] + bias[f];
                if (RELU) v = fmaxf(v, 0.f);
                C[(long)r * ldc + f] = v;
                if (BFOUT) hbf_out[(long)r * F + f] = f2bf(v);
            }
        }
    }
}

// GIN layer-1 GEMM with fused pre: A_eff = (1+eps)*h_prev + agg, relu epilogue.
__global__ __launch_bounds__(256) void gemm_gin1_kernel(
    const float* __restrict__ hp,            // feats slice, stride CAT
    const float* __restrict__ agg,           // dense [N][96]
    const float* __restrict__ eps_arr, int li,
    const float* __restrict__ W,
    const float* __restrict__ bias,
    float* __restrict__ C,                   // dense [N][96]
    int M)
{
    constexpr int BM = 64, BK = 32;
    __shared__ float As[BM][BK + 1];
    __shared__ float Ws[BK][HH];

    const int tid = threadIdx.x;
    const int ty = tid >> 4, tx = tid & 15;
    const int m0 = blockIdx.x * BM;
    const float e1 = 1.f + eps_arr[li];

    float acc[4][6];
#pragma unroll
    for (int i = 0; i < 4; ++i)
#pragma unroll
        for (int j = 0; j < 6; ++j) acc[i][j] = 0.f;

    for (int k0 = 0; k0 < HH; k0 += BK) {
        __syncthreads();
#pragma unroll
        for (int i = 0; i < (BM * BK) / 256; ++i) {
            int idx = i * 256 + tid;
            int r = idx >> 5, c = idx & 31;
            int gr = m0 + r;
            As[r][c] = (gr < M)
                ? e1 * hp[(long)gr * CAT + k0 + c] + agg[(long)gr * HH + k0 + c]
                : 0.f;
        }
#pragma unroll
        for (int i = 0; i < (BK * HH) / 256; ++i) {
            int idx = i * 256 + tid;
            int k = idx / HH, f = idx % HH;
            Ws[k][f] = W[(long)(k0 + k) * HH + f];
        }
        __syncthreads();
#pragma unroll
        for (int k = 0; k < BK; ++k) {
            float a[4], w[6];
#pragma unroll
            for (int i = 0; i < 4; ++i) a[i] = As[ty + i * 16][k];
#pragma unroll
            for (int j = 0; j < 6; ++j) w[j] = Ws[k][tx + j * 16];
#pragma unroll
            for (int i = 0; i < 4; ++i)
#pragma unroll
                for (int j = 0; j < 6; ++j)
                    acc[i][j] = fmaf(a[i], w[j], acc[i][j]);
        }
    }

#pragma unroll
    for (int i = 0; i < 4; ++i) {
        int r = m0 + ty + i * 16;
        if (r < M) {
#pragma unroll
            for (int j = 0; j < 6; ++j) {
                int f = tx + j * 16;
                C[(long)r * HH + f] = fmaxf(acc[i][j] + bias[f], 0.f);
            }
        }
    }
}

// ---------------- CSR build: hist -> scan -> scatter -----------------------------
__global__ void zero_int_kernel(int* __restrict__ p, int n)
{
    int i = blockIdx.x * blockDim.x + threadIdx.x;
    if (i < n) p[i] = 0;
}

__global__ void hist_kernel(const int* __restrict__ col, int* __restrict__ cnt, int E)
{
    int e = blockIdx.x * blockDim.x + threadIdx.x;
    if (e < E) atomicAdd(&cnt[col[e]], 1);
}

__global__ void scan1_kernel(const int* __restrict__ cnt, int* __restrict__ start,
                             int* __restrict__ bsum, int N)
{
    __shared__ int s[256];
    int tid = threadIdx.x;
    int i = blockIdx.x * 256 + tid;
    int v = (i < N) ? cnt[i] : 0;
    s[tid] = v;
    __syncthreads();
#pragma unroll
    for (int off = 1; off < 256; off <<= 1) {
        int t = (tid >= off) ? s[tid - off] : 0;
        __syncthreads();
        s[tid] += t;
        __syncthreads();
    }
    if (i < N) start[i] = s[tid] - v;
    if (tid == 255) bsum[blockIdx.x] = s[255];
}

__global__ void scan2_kernel(int* __restrict__ bsum, int nb)
{
    __shared__ int s[256];
    int tid = threadIdx.x;
    int v = (tid < nb) ? bsum[tid] : 0;
    s[tid] = v;
    __syncthreads();
#pragma unroll
    for (int off = 1; off < 256; off <<= 1) {
        int t = (tid >= off) ? s[tid - off] : 0;
        __syncthreads();
        s[tid] += t;
        __syncthreads();
    }
    if (tid < nb) bsum[tid] = s[tid] - v;
}

__global__ void scan3_kernel(int* __restrict__ start, const int* __restrict__ bsum,
                             int* __restrict__ cursor, int N, int E)
{
    int i = blockIdx.x * blockDim.x + threadIdx.x;
    if (i < N) {
        int f = start[i] + bsum[i >> 8];
        start[i] = f;
        cursor[i] = f;
    } else if (i == N) {
        start[N] = E;
    }
}

__global__ void scatter_kernel(const int* __restrict__ row, const int* __restrict__ col,
                               int* __restrict__ cursor,
                               int* __restrict__ edge_order, int* __restrict__ row_sorted,
                               int E)
{
    int e = blockIdx.x * blockDim.x + threadIdx.x;
    if (e < E) {
        int c = col[e];
        int p = atomicAdd(&cursor[c], 1);
        edge_order[p] = e;
        row_sorted[p] = row[e];
    }
}

// permute edge_attr into CSR order, f32 -> bf16
__global__ void permute_ea_kernel(const float* __restrict__ ea,
                                  const int* __restrict__ edge_order,
                                  unsigned short* __restrict__ eas, int E)
{
    int p = blockIdx.x * blockDim.x + threadIdx.x;
    if (p >= E) return;
    const float* src = ea + (size_t)edge_order[p] * EDGEF;
    f32x4 v0 = *(const f32x4*)(src);
    f32x4 v1 = *(const f32x4*)(src + 4);
    f32x4 v2 = *(const f32x4*)(src + 8);
    f32x4 v3 = *(const f32x4*)(src + 12);
    bf16x8 o0, o1;
#pragma unroll
    for (int j = 0; j < 4; ++j) {
        o0[j] = (short)f2bf(v0[j]); o0[4 + j] = (short)f2bf(v1[j]);
        o1[j] = (short)f2bf(v2[j]); o1[4 + j] = (short)f2bf(v3[j]);
    }
    *(bf16x8*)(eas + (size_t)p * EDGEF) = o0;
    *(bf16x8*)(eas + (size_t)p * EDGEF + 8) = o1;
}

// ---------------- node-centric MFMA edge kernel ----------------------------------
// One wave per destination node. Per 16-edge batch: h rows prefetched whole
// (3x16B/lane at batch start, latency hidden under GEMM1), parked in the freed
// s_t wave slice after bt-frag extraction; epilogue reads hv from LDS.
template <bool GCN>
__global__ __launch_bounds__(256, 4) void edge_kernel(
    const unsigned short* __restrict__ ea_sorted,
    const int* __restrict__ row_sorted,
    const int* __restrict__ seg_start,
    const float* __restrict__ bw1, const float* __restrict__ bb1,
    const float* __restrict__ bw2, const float* __restrict__ bb2,
    const unsigned short* __restrict__ hbf,
    const float* __restrict__ dinv,
    float* __restrict__ agg,
    int N)
{
    __shared__ __align__(16) short s_bw2T[96][104];   // bw2^T bf16 [f][k] 19968B
    __shared__ __align__(16) short s_bw1T[96][16];    // bw1^T bf16 [f][k]  3072B
    __shared__ __align__(16) short s_t[4][16][104];   // per-wave: t, then h 13312B
    __shared__ float s_bias[192];                     // bb1 | bb2            768B

    const int tid = threadIdx.x;
    const int lane = tid & 63;
    const int w = tid >> 6;
    const int lr = lane & 15;
    const int lg = lane >> 4;

    for (int idx = tid; idx < HH * HH; idx += 256) {
        int k = idx / HH, f = idx - k * HH;
        s_bw2T[f][k] = (short)f2bf(bw2[idx]);
    }
    for (int idx = tid; idx < EDGEF * HH; idx += 256) {
        int k = idx / HH, f = idx - k * HH;
        s_bw1T[f][k] = (short)f2bf(bw1[idx]);
    }
    if (tid < HH) { s_bias[tid] = bb1[tid]; s_bias[HH + tid] = bb2[tid]; }
    __syncthreads();

    const f32x4 zf = {0.f, 0.f, 0.f, 0.f};
    const int nwaves = gridDim.x * 4;

    for (int c = blockIdx.x * 4 + w; c < N; c += nwaves) {
        const int s0 = seg_start[c];
        const int s1 = seg_start[c + 1];
        float dinv_c = GCN ? dinv[c] : 1.f;

        f32x4 acc[6];
#pragma unroll
        for (int ft = 0; ft < 6; ++ft) acc[ft] = zf;

        for (int b = s0; b < s1; b += 16) {
            const int epos = b + lr;
            const bool vld = (epos < s1);
            const int epc = vld ? epos : s0;
            const int r = row_sorted[epc];

            // prefetch full h row (lane (lr,lg) covers 48B chunk lg of row lr)
            const unsigned short* hrow = hbf + (size_t)r * HH + 24 * lg;
            bf16x8 h0 = *(const bf16x8*)(hrow);
            bf16x8 h1 = *(const bf16x8*)(hrow + 8);
            bf16x8 h2 = *(const bf16x8*)(hrow + 16);

            float nrm = GCN ? dinv[r] * dinv_c : 1.f;

            // A-frag: sequential 16B bf16 load (k<16 real, rest zero)
            bf16x8 ae;
#pragma unroll
            for (int j = 0; j < 8; ++j) ae[j] = 0;
            if (lg < 2)
                ae = *(const bf16x8*)(ea_sorted + (size_t)epc * EDGEF + 8 * lg);

            // GEMM1 + bias + relu -> s_t (t layout [edge][feat])
#pragma unroll
            for (int ft = 0; ft < 6; ++ft) {
                bf16x8 b1;
#pragma unroll
                for (int j = 0; j < 8; ++j) b1[j] = 0;
                if (lg < 2)
                    b1 = *(const bf16x8*)&s_bw1T[lr + 16 * ft][8 * lg];
                f32x4 tacc = __builtin_amdgcn_mfma_f32_16x16x32_bf16(ae, b1, zf, 0, 0, 0);
                float bsv = s_bias[lr + 16 * ft];
#pragma unroll
                for (int reg = 0; reg < 4; ++reg) {
                    float v = fmaxf(tacc[reg] + bsv, 0.f);
                    s_t[w][4 * lg + reg][lr + 16 * ft] = (short)f2bf(v);
                }
            }
            __builtin_amdgcn_wave_barrier();    // t writes before bt reads

            // GEMM2 B-frags: t^T, col=edge=lr
            bf16x8 bt[3];
#pragma unroll
            for (int kt = 0; kt < 3; ++kt)
                bt[kt] = *(const bf16x8*)&s_t[w][lr][8 * lg + 32 * kt];
            __builtin_amdgcn_wave_barrier();    // bt reads before h overwrites

            // park h rows in the freed slice (lane (lr,lg) -> row lr, chunk lg)
            *(bf16x8*)&s_t[w][lr][24 * lg]      = h0;
            *(bf16x8*)&s_t[w][lr][24 * lg + 8]  = h1;
            *(bf16x8*)&s_t[w][lr][24 * lg + 16] = h2;
            __builtin_amdgcn_wave_barrier();    // h writes before hv reads

            // GEMM2 (swapped) + epilogue
#pragma unroll
            for (int ft = 0; ft < 6; ++ft) {
                f32x4 ee = zf;
#pragma unroll
                for (int kt = 0; kt < 3; ++kt) {
                    bf16x8 aw = *(const bf16x8*)&s_bw2T[lr + 16 * ft][8 * lg + 32 * kt];
                    ee = __builtin_amdgcn_mfma_f32_16x16x32_bf16(aw, bt[kt], ee, 0, 0, 0);
                }
                const int fb = 16 * ft + 4 * lg;
                f32x4 bb = *(const f32x4*)&s_bias[HH + fb];
                ubf16x4 hv = *(const ubf16x4*)&s_t[w][lr][fb];
#pragma unroll
                for (int reg = 0; reg < 4; ++reg) {
                    float m = fmaxf(bf2f(hv[reg]) + ee[reg] + bb[reg], 0.f) * nrm;
                    acc[ft][reg] += vld ? m : 0.f;
                }
            }
        }

        // reduce over the 16-edge lane dimension
#pragma unroll
        for (int ft = 0; ft < 6; ++ft) {
#pragma unroll
            for (int reg = 0; reg < 4; ++reg) {
                float v = acc[ft][reg];
                v += __shfl_xor(v, 1);
                v += __shfl_xor(v, 2);
                v += __shfl_xor(v, 4);
                v += __shfl_xor(v, 8);
                acc[ft][reg] = v;
            }
        }
        if (lr == 0) {
#pragma unroll
            for (int ft = 0; ft < 6; ++ft)
                *(f32x4*)&agg[(size_t)c * HH + 16 * ft + 4 * lg] = acc[ft];
        }
    }
}

// ---------------- small elementwise kernels --------------------------------------
__global__ void deg_init_kernel(float* __restrict__ deg, int N)
{
    int i = blockIdx.x * blockDim.x + threadIdx.x;
    if (i < N) deg[i] = 1.f;
}

__global__ void deg_accum_kernel(const int* __restrict__ row, float* __restrict__ deg, int E)
{
    int e = blockIdx.x * blockDim.x + threadIdx.x;
    if (e < E) atomicAdd(&deg[row[e]], 1.f);
}

__global__ void dinv_kernel(const float* __restrict__ deg, float* __restrict__ dinv, int N)
{
    int i = blockIdx.x * blockDim.x + threadIdx.x;
    if (i < N) dinv[i] = rsqrtf(deg[i]);
}

__global__ void gcn_epilogue_kernel(
    const float* __restrict__ agg, const float* __restrict__ hbuf,
    const float* __restrict__ root, const float* __restrict__ deg,
    const float* __restrict__ gamma, const float* __restrict__ beta,
    const float* __restrict__ mean, const float* __restrict__ var,
    float* __restrict__ feats, unsigned short* __restrict__ hbf, int N)
{
    int idx = blockIdx.x * blockDim.x + threadIdx.x;
    if (idx >= N * HH) return;
    int n = idx / HH, f = idx - n * HH;
    float self = fmaxf(hbuf[idx] + root[f], 0.f) / deg[n];
    float v = fmaxf(agg[idx] + self, 0.f);
    v = (v - mean[f]) * rsqrtf(var[f] + 1e-5f) * gamma[f] + beta[f];
    feats[(long)n * CAT + f] = v;
    hbf[idx] = f2bf(v);
}

__global__ void gin_post_kernel(
    const float* __restrict__ zout,
    const float* __restrict__ gamma, const float* __restrict__ beta,
    const float* __restrict__ mean, const float* __restrict__ var,
    float* __restrict__ feats, int slot, unsigned short* __restrict__ hbf, int N)
{
    int idx = blockIdx.x * blockDim.x + threadIdx.x;
    if (idx >= N * HH) return;
    int n = idx / HH, f = idx - n * HH;
    float v = fmaxf(zout[idx], 0.f);
    v = (v - mean[f]) * rsqrtf(var[f] + 1e-5f) * gamma[f] + beta[f];
    feats[(long)n * CAT + slot * HH + f] = v;
    hbf[idx] = f2bf(v);
}

// ---------------- launch ----------------------------------------------------------
extern "C" void kernel_launch(void* const* d_in, const int* in_sizes, int n_in,
                              void* d_out, int out_size, void* d_ws, size_t ws_size,
                              hipStream_t stream)
{
    const float* x         = (const float*)d_in[0];
    const int*   eidx      = (const int*)d_in[1];
    const float* edge_attr = (const float*)d_in[2];
    const float* gcn_lin_w = (const float*)d_in[3];
    const float* gcn_lin_b = (const float*)d_in[4];
    const float* gcn_root  = (const float*)d_in[5];
    const float* gcn_bw1   = (const float*)d_in[6];
    const float* gcn_bb1   = (const float*)d_in[7];
    const float* gcn_bw2   = (const float*)d_in[8];
    const float* gcn_bb2   = (const float*)d_in[9];
    const float* gin_bw1   = (const float*)d_in[10];
    const float* gin_bb1   = (const float*)d_in[11];
    const float* gin_bw2   = (const float*)d_in[12];
    const float* gin_bb2   = (const float*)d_in[13];
    const float* gin_mw1   = (const float*)d_in[14];
    const float* gin_mb1   = (const float*)d_in[15];
    const float* gin_mw2   = (const float*)d_in[16];
    const float* gin_mb2   = (const float*)d_in[17];
    const float* gin_eps   = (const float*)d_in[18];
    const float* bn_gamma  = (const float*)d_in[19];
    const float* bn_beta   = (const float*)d_in[20];
    const float* bn_mean   = (const float*)d_in[21];
    const float* bn_var    = (const float*)d_in[22];
    const float* fc1_w     = (const float*)d_in[23];
    const float* fc1_b     = (const float*)d_in[24];
    const float* fc2_w     = (const float*)d_in[25];
    const float* fc2_b     = (const float*)d_in[26];
    float* out = (float*)d_out;

    const int N = in_sizes[0] / 128;   // 50000
    const int E = in_sizes[1] / 2;     // 800000
    const int* row = eidx;
    const int* col = eidx + E;

    // ws layout (bytes)
    char* ws = (char*)d_ws;
    float* deg        = (float*)(ws);                          // N f32
    float* dinv       = (float*)(ws + (size_t)256 * 1024);     // N f32
    int*   seg_start  = (int*)(ws + (size_t)512 * 1024);       // N+1
    int*   cursor     = (int*)(ws + (size_t)768 * 1024);       // N
    int*   bsum       = (int*)(ws + (size_t)1024 * 1024);      // 256
    int*   edge_order = (int*)(ws + (size_t)(1024 + 64) * 1024);  // E
    int*   row_sorted = edge_order + E;                        // E (ends ~7.5MB)
    unsigned short* ea_sorted = (unsigned short*)(ws + (size_t)8 * 1024 * 1024);   // E*16 bf16
    unsigned short* hbf = (unsigned short*)(ws + (size_t)34 * 1024 * 1024);        // N*96 bf16
    float* hbuf  = (float*)(ws + (size_t)44 * 1024 * 1024);    // N*96 f32
    float* tmp   = hbuf + (size_t)N * HH;                      // N*96
    float* feats = tmp + (size_t)N * HH;                       // N*288
    float* agg = tmp;

    const int ew_blocks = 1024;
    const int nh_grid = (N * HH + 255) / 256;
    const int gemm_grid = (N + 63) / 64;
    const int e_grid = (E + 255) / 256;
    const int n_grid = (N + 255) / 256;
    const int nchunks = (N + 255) / 256;

    // ---- degrees + CSR build (once per call) ----
    deg_init_kernel<<<n_grid, 256, 0, stream>>>(deg, N);
    deg_accum_kernel<<<e_grid, 256, 0, stream>>>(row, deg, E);
    dinv_kernel<<<n_grid, 256, 0, stream>>>(deg, dinv, N);
    zero_int_kernel<<<n_grid, 256, 0, stream>>>(cursor, N);
    hist_kernel<<<e_grid, 256, 0, stream>>>(col, cursor, E);
    scan1_kernel<<<nchunks, 256, 0, stream>>>(cursor, seg_start, bsum, N);
    scan2_kernel<<<1, 256, 0, stream>>>(bsum, nchunks);
    scan3_kernel<<<(N + 256) / 256, 256, 0, stream>>>(seg_start, bsum, cursor, N, E);
    scatter_kernel<<<e_grid, 256, 0, stream>>>(row, col, cursor, edge_order, row_sorted, E);
    permute_ea_kernel<<<e_grid, 256, 0, stream>>>(edge_attr, edge_order, ea_sorted, E);

    // ---- layer 0: GCN ----
    gemm_kernel<HH, false, true><<<gemm_grid, 256, 0, stream>>>(
        x, 128, gcn_lin_w, gcn_lin_b, hbuf, HH, hbf, N, 128);
    edge_kernel<true><<<ew_blocks, 256, 0, stream>>>(ea_sorted, row_sorted, seg_start,
                                                     gcn_bw1, gcn_bb1, gcn_bw2, gcn_bb2,
                                                     hbf, dinv, agg, N);
    gcn_epilogue_kernel<<<nh_grid, 256, 0, stream>>>(agg, hbuf, gcn_root, deg,
                                                     bn_gamma, bn_beta, bn_mean, bn_var,
                                                     feats, hbf, N);

    // ---- layers 1..2: GIN ----
    for (int i = 0; i < 2; ++i) {
        const float* h_prev = feats + i * HH;   // stride CAT
        edge_kernel<false><<<ew_blocks, 256, 0, stream>>>(
            ea_sorted, row_sorted, seg_start,
            gin_bw1 + (size_t)i * EDGEF * HH, gin_bb1 + i * HH,
            gin_bw2 + (size_t)i * HH * HH, gin_bb2 + i * HH,
            hbf, dinv, agg, N);
        // z = (1+eps)*h + agg fused into mw1 GEMM; -> hbuf (free here)
        gemm_gin1_kernel<<<gemm_grid, 256, 0, stream>>>(
            h_prev, agg, gin_eps, i,
            gin_mw1 + (size_t)i * HH * HH, gin_mb1 + i * HH, hbuf, N);
        // mw2: hbuf -> tmp (agg dead now)
        gemm_kernel<HH, false, false><<<gemm_grid, 256, 0, stream>>>(
            hbuf, HH, gin_mw2 + (size_t)i * HH * HH, gin_mb2 + i * HH,
            tmp, HH, (unsigned short*)nullptr, N, HH);
        gin_post_kernel<<<nh_grid, 256, 0, stream>>>(
            tmp, bn_gamma + (i + 1) * HH, bn_beta + (i + 1) * HH,
            bn_mean + (i + 1) * HH, bn_var + (i + 1) * HH, feats, i + 1, hbf, N);
    }

    // ---- head ----
    gemm_kernel<HH, true, false><<<gemm_grid, 256, 0, stream>>>(
        feats, CAT, fc1_w, fc1_b, hbuf, HH, (unsigned short*)nullptr, N, CAT);
    gemm_kernel<64, false, false><<<gemm_grid, 256, 0, stream>>>(
        hbuf, HH, fc2_w, fc2_b, out, 64, (unsigned short*)nullptr, N, HH);
}